// Round 1
// baseline (1830.459 us; speedup 1.0000x reference)
//
#include <hip/hip_runtime.h>

// Problem: B=128 trajectories, N vars, M clauses, K=3 literals/clause.
// Inputs (in_sizes order): v(B*N) f32, xl(B*M) f32, xs(B*M) f32, param(6) f32,
//                          input_sign(B*M*K) f32, input_idx(B*M*K) i32
// Outputs concat: C(B*M), grad_v(B*N), dxl(B*M), dxs(B*M)  -- all f32

__global__ __launch_bounds__(256) void zero_f4(float4* __restrict__ p, int n4) {
    int i = blockIdx.x * blockDim.x + threadIdx.x;
    int stride = gridDim.x * blockDim.x;
    for (; i < n4; i += stride) p[i] = make_float4(0.f, 0.f, 0.f, 0.f);
}

__global__ __launch_bounds__(256) void or_kernel(
    const float* __restrict__ v,
    const float* __restrict__ xl,
    const float* __restrict__ xs,
    const float* __restrict__ param,
    const float* __restrict__ sign,
    const int*   __restrict__ idx,
    float* __restrict__ outC,
    float* __restrict__ gradv,
    float* __restrict__ outdxl,
    float* __restrict__ outdxs,
    int N, int M)
{
    const int m = blockIdx.x * blockDim.x + threadIdx.x;
    const int b = blockIdx.y;
    if (m >= M) return;

    const long bm = (long)b * M + m;
    const long bm3 = bm * 3;

    // contiguous 12B per thread -> coalesced across the wave
    const int   i0 = idx[bm3 + 0], i1 = idx[bm3 + 1], i2 = idx[bm3 + 2];
    const float s0 = sign[bm3 + 0], s1 = sign[bm3 + 1], s2 = sign[bm3 + 2];

    const float* __restrict__ vb = v + (long)b * N;
    const float a0 = vb[i0] * s0;
    const float a1 = vb[i1] * s1;
    const float a2 = vb[i2] * s2;

    // top-2 with jax.lax.top_k tie semantics (first occurrence wins argmax)
    int k0; float m0, m1;
    if (a0 >= a1) {
        if (a0 >= a2) { k0 = 0; m0 = a0; m1 = fmaxf(a1, a2); }
        else          { k0 = 2; m0 = a2; m1 = fmaxf(a0, a1); }
    } else {
        if (a1 >= a2) { k0 = 1; m0 = a1; m1 = fmaxf(a0, a2); }
        else          { k0 = 2; m0 = a2; m1 = fmaxf(a0, a1); }
    }

    const float C  = (1.f - m0) * 0.5f;   // transformed max  == clause distance
    const float T2 = (1.f - m1) * 0.5f;   // transformed second

    const float alpha = param[0], beta = param[1], gamma = param[2];
    const float delta = param[3], eps  = param[4], zeta  = param[5];

    const float xlv = xl[bm], xsv = xs[bm];
    const float gl = xlv * xsv;                       // G scale
    const float gr = (1.f + zeta * xlv) * (1.f - xsv); // R scale
    const float rC = C * gr;

    const float g0 = (k0 == 0 ? T2 : C) * gl + (k0 == 0 ? rC : 0.f);
    const float g1 = (k0 == 1 ? T2 : C) * gl + (k0 == 1 ? rC : 0.f);
    const float g2 = (k0 == 2 ? T2 : C) * gl + (k0 == 2 ? rC : 0.f);

    float* __restrict__ gb = gradv + (long)b * N;
    atomicAdd(&gb[i0], -g0 * s0);
    atomicAdd(&gb[i1], -g1 * s1);
    atomicAdd(&gb[i2], -g2 * s2);

    outC[bm]   = C;
    outdxl[bm] = -alpha * (C - delta);
    outdxs[bm] = -beta * (xsv + eps) * (C - gamma);
}

extern "C" void kernel_launch(void* const* d_in, const int* in_sizes, int n_in,
                              void* d_out, int out_size, void* d_ws, size_t ws_size,
                              hipStream_t stream) {
    const float* v     = (const float*)d_in[0];
    const float* xl    = (const float*)d_in[1];
    const float* xs    = (const float*)d_in[2];
    const float* param = (const float*)d_in[3];
    const float* sign  = (const float*)d_in[4];
    const int*   idx   = (const int*)d_in[5];

    const int B = 128;
    const int N = in_sizes[0] / B;   // 20000
    const int M = in_sizes[1] / B;   // 85400

    float* outC   = (float*)d_out;
    float* gradv  = outC   + (size_t)in_sizes[1];
    float* outdxl = gradv  + (size_t)in_sizes[0];
    float* outdxs = outdxl + (size_t)in_sizes[1];

    // zero-init grad_v region (harness poisons d_out with 0xAA before each call)
    const int n4 = in_sizes[0] / 4;  // B*N divisible by 4
    zero_f4<<<dim3((n4 + 255) / 256), dim3(256), 0, stream>>>((float4*)gradv, n4);

    dim3 grid((M + 255) / 256, B);
    or_kernel<<<grid, dim3(256), 0, stream>>>(v, xl, xs, param, sign, idx,
                                              outC, gradv, outdxl, outdxs, N, M);
}

// Round 2
// 577.046 us; speedup vs baseline: 3.1721x; 3.1721x over previous
//
#include <hip/hip_runtime.h>

// B=128 trajectories, N=20000 vars, M=85400 clauses, K=3 literals/clause.
// Inputs: v(B*N) f32, xl(B*M) f32, xs(B*M) f32, param(6) f32,
//         input_sign(B*M*K) f32, input_idx(B*M*K) i32
// Outputs concat: C(B*M), grad_v(B*N), dxl(B*M), dxs(B*M)  -- all f32

#define NMAX 20000     // LDS privatization buffer (80 KB -> 2 blocks/CU of 160 KB)
#define BPB  4         // clause-chunks (blocks) per batch element

__device__ __forceinline__ void clause_math(
    float a0, float a1, float a2, float xlv, float xsv, float zeta,
    float& C, float& g0, float& g1, float& g2)
{
    // top-2 with jax.lax.top_k tie semantics (first occurrence wins argmax)
    int k0; float m0, m1;
    if (a0 >= a1) {
        if (a0 >= a2) { k0 = 0; m0 = a0; m1 = fmaxf(a1, a2); }
        else          { k0 = 2; m0 = a2; m1 = fmaxf(a0, a1); }
    } else {
        if (a1 >= a2) { k0 = 1; m0 = a1; m1 = fmaxf(a0, a2); }
        else          { k0 = 2; m0 = a2; m1 = fmaxf(a0, a1); }
    }
    C = (1.f - m0) * 0.5f;
    const float T2 = (1.f - m1) * 0.5f;
    const float gl = xlv * xsv;
    const float rC = C * ((1.f + zeta * xlv) * (1.f - xsv));
    g0 = (k0 == 0 ? T2 : C) * gl + (k0 == 0 ? rC : 0.f);
    g1 = (k0 == 1 ? T2 : C) * gl + (k0 == 1 ? rC : 0.f);
    g2 = (k0 == 2 ? T2 : C) * gl + (k0 == 2 ? rC : 0.f);
}

// ---------- fast path: LDS-privatized scatter ----------
__global__ __launch_bounds__(256, 2) void or_priv(
    const float* __restrict__ v,
    const float* __restrict__ xl,
    const float* __restrict__ xs,
    const float* __restrict__ param,
    const float* __restrict__ sign,
    const int*   __restrict__ idx,
    float* __restrict__ outC,
    float* __restrict__ outdxl,
    float* __restrict__ outdxs,
    float* __restrict__ partial,   // [BPB][B][N]
    int N, int M, int chunk)
{
    __shared__ float sg[NMAX];
    const int j = blockIdx.x;
    const int b = blockIdx.y;
    const int tid = threadIdx.x;

    for (int i = tid; i < N; i += 256) sg[i] = 0.f;
    __syncthreads();

    const float alpha = param[0], beta = param[1], gamma = param[2];
    const float delta = param[3], eps  = param[4], zeta  = param[5];
    const float* __restrict__ vb = v + (size_t)b * N;

    const int mstart = j * chunk;
    const int mend   = min(M, mstart + chunk);
    for (int m = mstart + tid; m < mend; m += 256) {
        const size_t bm  = (size_t)b * M + m;
        const size_t bm3 = bm * 3;
        const int   i0 = idx[bm3 + 0], i1 = idx[bm3 + 1], i2 = idx[bm3 + 2];
        const float s0 = sign[bm3 + 0], s1 = sign[bm3 + 1], s2 = sign[bm3 + 2];
        const float a0 = vb[i0] * s0, a1 = vb[i1] * s1, a2 = vb[i2] * s2;
        const float xlv = xl[bm], xsv = xs[bm];

        float C, g0, g1, g2;
        clause_math(a0, a1, a2, xlv, xsv, zeta, C, g0, g1, g2);

        atomicAdd(&sg[i0], -g0 * s0);   // ds_add_f32 — LDS-local, cheap
        atomicAdd(&sg[i1], -g1 * s1);
        atomicAdd(&sg[i2], -g2 * s2);

        outC[bm]   = C;
        outdxl[bm] = -alpha * (C - delta);
        outdxs[bm] = -beta * (xsv + eps) * (C - gamma);
    }
    __syncthreads();

    float* __restrict__ pj = partial + ((size_t)j * gridDim.y + b) * N;
    for (int i = tid; i < N; i += 256) pj[i] = sg[i];
}

__global__ __launch_bounds__(256) void reduce4(
    const float4* __restrict__ p, float4* __restrict__ out, int n4, int stride4)
{
    int i = blockIdx.x * 256 + threadIdx.x;
    const int gs = gridDim.x * 256;
    for (; i < n4; i += gs) {
        const float4 a = p[i];
        const float4 b = p[i + stride4];
        const float4 c = p[i + 2 * stride4];
        const float4 d = p[i + 3 * stride4];
        out[i] = make_float4(a.x + b.x + c.x + d.x,
                             a.y + b.y + c.y + d.y,
                             a.z + b.z + c.z + d.z,
                             a.w + b.w + c.w + d.w);
    }
}

// ---------- fallback path (round-1, global atomics) ----------
__global__ __launch_bounds__(256) void zero_f4(float4* __restrict__ p, int n4) {
    int i = blockIdx.x * blockDim.x + threadIdx.x;
    int stride = gridDim.x * blockDim.x;
    for (; i < n4; i += stride) p[i] = make_float4(0.f, 0.f, 0.f, 0.f);
}

__global__ __launch_bounds__(256) void or_kernel(
    const float* __restrict__ v, const float* __restrict__ xl,
    const float* __restrict__ xs, const float* __restrict__ param,
    const float* __restrict__ sign, const int* __restrict__ idx,
    float* __restrict__ outC, float* __restrict__ gradv,
    float* __restrict__ outdxl, float* __restrict__ outdxs, int N, int M)
{
    const int m = blockIdx.x * blockDim.x + threadIdx.x;
    const int b = blockIdx.y;
    if (m >= M) return;
    const size_t bm = (size_t)b * M + m;
    const size_t bm3 = bm * 3;
    const int   i0 = idx[bm3 + 0], i1 = idx[bm3 + 1], i2 = idx[bm3 + 2];
    const float s0 = sign[bm3 + 0], s1 = sign[bm3 + 1], s2 = sign[bm3 + 2];
    const float* __restrict__ vb = v + (size_t)b * N;
    const float a0 = vb[i0] * s0, a1 = vb[i1] * s1, a2 = vb[i2] * s2;
    const float xlv = xl[bm], xsv = xs[bm];
    const float alpha = param[0], beta = param[1], gamma = param[2];
    const float delta = param[3], eps  = param[4], zeta  = param[5];

    float C, g0, g1, g2;
    clause_math(a0, a1, a2, xlv, xsv, zeta, C, g0, g1, g2);

    float* __restrict__ gb = gradv + (size_t)b * N;
    atomicAdd(&gb[i0], -g0 * s0);
    atomicAdd(&gb[i1], -g1 * s1);
    atomicAdd(&gb[i2], -g2 * s2);

    outC[bm]   = C;
    outdxl[bm] = -alpha * (C - delta);
    outdxs[bm] = -beta * (xsv + eps) * (C - gamma);
}

extern "C" void kernel_launch(void* const* d_in, const int* in_sizes, int n_in,
                              void* d_out, int out_size, void* d_ws, size_t ws_size,
                              hipStream_t stream) {
    const float* v     = (const float*)d_in[0];
    const float* xl    = (const float*)d_in[1];
    const float* xs    = (const float*)d_in[2];
    const float* param = (const float*)d_in[3];
    const float* sign  = (const float*)d_in[4];
    const int*   idx   = (const int*)d_in[5];

    const int B = 128;
    const int N = in_sizes[0] / B;   // 20000
    const int M = in_sizes[1] / B;   // 85400

    float* outC   = (float*)d_out;
    float* gradv  = outC   + (size_t)in_sizes[1];
    float* outdxl = gradv  + (size_t)in_sizes[0];
    float* outdxs = outdxl + (size_t)in_sizes[1];

    const size_t bn = (size_t)B * N;
    const size_t ws_need = (size_t)BPB * bn * sizeof(float);

    if (N <= NMAX && ws_size >= ws_need && (bn % 4) == 0) {
        // fast path: LDS privatization + partial buffers + reduce
        float* partial = (float*)d_ws;
        const int chunk = (M + BPB - 1) / BPB;
        dim3 grid(BPB, B);
        or_priv<<<grid, dim3(256), 0, stream>>>(v, xl, xs, param, sign, idx,
                                                outC, outdxl, outdxs, partial,
                                                N, M, chunk);
        const int n4 = (int)(bn / 4);
        const int rblocks = min(2048, (n4 + 255) / 256);
        reduce4<<<dim3(rblocks), dim3(256), 0, stream>>>(
            (const float4*)partial, (float4*)gradv, n4, n4);
    } else {
        // fallback: global atomics
        const int n4 = (int)(bn / 4);
        zero_f4<<<dim3((n4 + 255) / 256), dim3(256), 0, stream>>>((float4*)gradv, n4);
        dim3 grid((M + 255) / 256, B);
        or_kernel<<<grid, dim3(256), 0, stream>>>(v, xl, xs, param, sign, idx,
                                                  outC, gradv, outdxl, outdxs, N, M);
    }
}

// Round 4
// 474.569 us; speedup vs baseline: 3.8571x; 1.2159x over previous
//
#include <hip/hip_runtime.h>

// B=128 trajectories, N=20000 vars, M=85400 clauses, K=3 literals/clause.
// Inputs: v(B*N) f32, xl(B*M) f32, xs(B*M) f32, param(6) f32,
//         input_sign(B*M*K) f32, input_idx(B*M*K) i32
// Outputs concat: C(B*M), grad_v(B*N), dxl(B*M), dxs(B*M)  -- all f32

#define NMAX 20000     // v-slice (80KB) + grad accumulator (80KB) = 160KB LDS = full CU
#define BPB  4         // clause-chunks (blocks) per batch element

// native clang vector types — required by __builtin_nontemporal_load/store
typedef int   int4v   __attribute__((ext_vector_type(4)));
typedef float float4v __attribute__((ext_vector_type(4)));

__device__ __forceinline__ void clause_math(
    float a0, float a1, float a2, float xlv, float xsv, float zeta,
    float& C, float& g0, float& g1, float& g2)
{
    // top-2 with jax.lax.top_k tie semantics (first occurrence wins argmax)
    int k0; float m0, m1;
    if (a0 >= a1) {
        if (a0 >= a2) { k0 = 0; m0 = a0; m1 = fmaxf(a1, a2); }
        else          { k0 = 2; m0 = a2; m1 = fmaxf(a0, a1); }
    } else {
        if (a1 >= a2) { k0 = 1; m0 = a1; m1 = fmaxf(a0, a2); }
        else          { k0 = 2; m0 = a2; m1 = fmaxf(a0, a1); }
    }
    C = (1.f - m0) * 0.5f;
    const float T2 = (1.f - m1) * 0.5f;
    const float gl = xlv * xsv;
    const float rC = C * ((1.f + zeta * xlv) * (1.f - xsv));
    g0 = (k0 == 0 ? T2 : C) * gl + (k0 == 0 ? rC : 0.f);
    g1 = (k0 == 1 ? T2 : C) * gl + (k0 == 1 ? rC : 0.f);
    g2 = (k0 == 2 ? T2 : C) * gl + (k0 == 2 ? rC : 0.f);
}

// ---------- fast path: v-slice + grad both in LDS ----------
__global__ __launch_bounds__(1024, 1) void or_priv2(
    const float* __restrict__ v,
    const float* __restrict__ xl,
    const float* __restrict__ xs,
    const float* __restrict__ param,
    const float* __restrict__ sign,
    const int*   __restrict__ idx,
    float* __restrict__ outC,
    float* __restrict__ outdxl,
    float* __restrict__ outdxs,
    float* __restrict__ partial,   // [BPB][B][N]
    int N, int M, int chunk)
{
    __shared__ float sv[NMAX];   // v slice for batch b
    __shared__ float sg[NMAX];   // grad accumulator
    const int j = blockIdx.x;
    const int b = blockIdx.y;
    const int tid = threadIdx.x;

    // stage v slice (coalesced float4) + zero grad
    {
        const float4v* __restrict__ v4 = (const float4v*)(v + (size_t)b * N);
        float4v* sv4 = (float4v*)sv;
        float4v* sg4 = (float4v*)sg;
        const int n4 = N >> 2;
        const float4v z = {0.f, 0.f, 0.f, 0.f};
        for (int i = tid; i < n4; i += 1024) {
            sv4[i] = v4[i];
            sg4[i] = z;
        }
        for (int i = (n4 << 2) + tid; i < N; i += 1024) {
            sv[i] = v[(size_t)b * N + i];
            sg[i] = 0.f;
        }
    }
    __syncthreads();

    const float alpha = param[0], beta = param[1], gamma = param[2];
    const float delta = param[3], eps  = param[4], zeta  = param[5];

    const int mstart = j * chunk;                 // chunk is a multiple of 4
    const int mend   = min(M, mstart + chunk);
    const int ngroups = (mend > mstart) ? ((mend - mstart + 3) >> 2) : 0;

    for (int g = tid; g < ngroups; g += 1024) {
        const int m0 = mstart + (g << 2);
        const size_t base = (size_t)b * M + m0;    // multiple of 4 -> 16B aligned

        if (m0 + 3 < mend) {
            const int4v*   __restrict__ ip = (const int4v*)(idx + base * 3);
            const float4v* __restrict__ sp = (const float4v*)(sign + base * 3);
            const int4v   ia = __builtin_nontemporal_load(ip + 0);
            const int4v   ib = __builtin_nontemporal_load(ip + 1);
            const int4v   ic = __builtin_nontemporal_load(ip + 2);
            const float4v sa = __builtin_nontemporal_load(sp + 0);
            const float4v sb = __builtin_nontemporal_load(sp + 1);
            const float4v sc = __builtin_nontemporal_load(sp + 2);
            const float4v xl4 = __builtin_nontemporal_load((const float4v*)(xl + base));
            const float4v xs4 = __builtin_nontemporal_load((const float4v*)(xs + base));

            const int   ii[12] = {ia.x, ia.y, ia.z, ia.w, ib.x, ib.y, ib.z, ib.w,
                                  ic.x, ic.y, ic.z, ic.w};
            const float ss[12] = {sa.x, sa.y, sa.z, sa.w, sb.x, sb.y, sb.z, sb.w,
                                  sc.x, sc.y, sc.z, sc.w};
            const float xlA[4] = {xl4.x, xl4.y, xl4.z, xl4.w};
            const float xsA[4] = {xs4.x, xs4.y, xs4.z, xs4.w};
            float Cv[4], dxlv[4], dxsv[4];

            #pragma unroll
            for (int c = 0; c < 4; ++c) {
                const int   i0 = ii[3*c], i1 = ii[3*c+1], i2 = ii[3*c+2];
                const float s0 = ss[3*c], s1 = ss[3*c+1], s2 = ss[3*c+2];
                const float a0 = sv[i0] * s0, a1 = sv[i1] * s1, a2 = sv[i2] * s2;
                float C, g0, g1, g2;
                clause_math(a0, a1, a2, xlA[c], xsA[c], zeta, C, g0, g1, g2);
                atomicAdd(&sg[i0], -g0 * s0);
                atomicAdd(&sg[i1], -g1 * s1);
                atomicAdd(&sg[i2], -g2 * s2);
                Cv[c]   = C;
                dxlv[c] = -alpha * (C - delta);
                dxsv[c] = -beta * (xsA[c] + eps) * (C - gamma);
            }
            const float4v cv  = {Cv[0], Cv[1], Cv[2], Cv[3]};
            const float4v lv  = {dxlv[0], dxlv[1], dxlv[2], dxlv[3]};
            const float4v svo = {dxsv[0], dxsv[1], dxsv[2], dxsv[3]};
            __builtin_nontemporal_store(cv,  (float4v*)(outC + base));
            __builtin_nontemporal_store(lv,  (float4v*)(outdxl + base));
            __builtin_nontemporal_store(svo, (float4v*)(outdxs + base));
        } else {
            for (int m = m0; m < mend; ++m) {
                const size_t bm  = (size_t)b * M + m;
                const size_t bm3 = bm * 3;
                const int   i0 = idx[bm3 + 0], i1 = idx[bm3 + 1], i2 = idx[bm3 + 2];
                const float s0 = sign[bm3 + 0], s1 = sign[bm3 + 1], s2 = sign[bm3 + 2];
                const float a0 = sv[i0] * s0, a1 = sv[i1] * s1, a2 = sv[i2] * s2;
                const float xlv = xl[bm], xsv = xs[bm];
                float C, g0, g1, g2;
                clause_math(a0, a1, a2, xlv, xsv, zeta, C, g0, g1, g2);
                atomicAdd(&sg[i0], -g0 * s0);
                atomicAdd(&sg[i1], -g1 * s1);
                atomicAdd(&sg[i2], -g2 * s2);
                outC[bm]   = C;
                outdxl[bm] = -alpha * (C - delta);
                outdxs[bm] = -beta * (xsv + eps) * (C - gamma);
            }
        }
    }
    __syncthreads();

    // flush grad accumulator to the per-(j,b) partial slab (coalesced float4)
    {
        float* __restrict__ pj = partial + ((size_t)j * gridDim.y + b) * N;
        const float4v* sg4 = (const float4v*)sg;
        const int n4 = N >> 2;
        for (int i = tid; i < n4; i += 1024)
            __builtin_nontemporal_store(sg4[i], (float4v*)pj + i);
        for (int i = (n4 << 2) + tid; i < N; i += 1024) pj[i] = sg[i];
    }
}

__global__ __launch_bounds__(256) void reduce4(
    const float4v* __restrict__ p, float4v* __restrict__ out, int n4, int stride4)
{
    int i = blockIdx.x * 256 + threadIdx.x;
    const int gs = gridDim.x * 256;
    for (; i < n4; i += gs) {
        const float4v a = p[i];
        const float4v b = p[i + stride4];
        const float4v c = p[i + 2 * stride4];
        const float4v d = p[i + 3 * stride4];
        out[i] = a + b + c + d;
    }
}

// ---------- fallback path (round-1, global atomics) ----------
__global__ __launch_bounds__(256) void zero_f4(float4v* __restrict__ p, int n4) {
    int i = blockIdx.x * blockDim.x + threadIdx.x;
    int stride = gridDim.x * blockDim.x;
    const float4v z = {0.f, 0.f, 0.f, 0.f};
    for (; i < n4; i += stride) p[i] = z;
}

__global__ __launch_bounds__(256) void or_kernel(
    const float* __restrict__ v, const float* __restrict__ xl,
    const float* __restrict__ xs, const float* __restrict__ param,
    const float* __restrict__ sign, const int* __restrict__ idx,
    float* __restrict__ outC, float* __restrict__ gradv,
    float* __restrict__ outdxl, float* __restrict__ outdxs, int N, int M)
{
    const int m = blockIdx.x * blockDim.x + threadIdx.x;
    const int b = blockIdx.y;
    if (m >= M) return;
    const size_t bm = (size_t)b * M + m;
    const size_t bm3 = bm * 3;
    const int   i0 = idx[bm3 + 0], i1 = idx[bm3 + 1], i2 = idx[bm3 + 2];
    const float s0 = sign[bm3 + 0], s1 = sign[bm3 + 1], s2 = sign[bm3 + 2];
    const float* __restrict__ vb = v + (size_t)b * N;
    const float a0 = vb[i0] * s0, a1 = vb[i1] * s1, a2 = vb[i2] * s2;
    const float xlv = xl[bm], xsv = xs[bm];
    const float alpha = param[0], beta = param[1], gamma = param[2];
    const float delta = param[3], eps  = param[4], zeta  = param[5];

    float C, g0, g1, g2;
    clause_math(a0, a1, a2, xlv, xsv, zeta, C, g0, g1, g2);

    float* __restrict__ gb = gradv + (size_t)b * N;
    atomicAdd(&gb[i0], -g0 * s0);
    atomicAdd(&gb[i1], -g1 * s1);
    atomicAdd(&gb[i2], -g2 * s2);

    outC[bm]   = C;
    outdxl[bm] = -alpha * (C - delta);
    outdxs[bm] = -beta * (xsv + eps) * (C - gamma);
}

extern "C" void kernel_launch(void* const* d_in, const int* in_sizes, int n_in,
                              void* d_out, int out_size, void* d_ws, size_t ws_size,
                              hipStream_t stream) {
    const float* v     = (const float*)d_in[0];
    const float* xl    = (const float*)d_in[1];
    const float* xs    = (const float*)d_in[2];
    const float* param = (const float*)d_in[3];
    const float* sign  = (const float*)d_in[4];
    const int*   idx   = (const int*)d_in[5];

    const int B = 128;
    const int N = in_sizes[0] / B;   // 20000
    const int M = in_sizes[1] / B;   // 85400

    float* outC   = (float*)d_out;
    float* gradv  = outC   + (size_t)in_sizes[1];
    float* outdxl = gradv  + (size_t)in_sizes[0];
    float* outdxs = outdxl + (size_t)in_sizes[1];

    const size_t bn = (size_t)B * N;
    const size_t ws_need = (size_t)BPB * bn * sizeof(float);

    if (N <= NMAX && ws_size >= ws_need && (bn % 4) == 0 && (M % 4) == 0) {
        float* partial = (float*)d_ws;
        // chunk: multiple of 4 so every group's base is 16B-aligned
        const int chunk = (((M + BPB - 1) / BPB) + 3) & ~3;
        dim3 grid(BPB, B);
        or_priv2<<<grid, dim3(1024), 0, stream>>>(v, xl, xs, param, sign, idx,
                                                  outC, outdxl, outdxs, partial,
                                                  N, M, chunk);
        const int n4 = (int)(bn / 4);
        const int rblocks = min(2048, (n4 + 255) / 256);
        reduce4<<<dim3(rblocks), dim3(256), 0, stream>>>(
            (const float4v*)partial, (float4v*)gradv, n4, n4);
    } else {
        const int n4 = (int)(bn / 4);
        zero_f4<<<dim3((n4 + 255) / 256), dim3(256), 0, stream>>>((float4v*)gradv, n4);
        dim3 grid((M + 255) / 256, B);
        or_kernel<<<grid, dim3(256), 0, stream>>>(v, xl, xs, param, sign, idx,
                                                  outC, gradv, outdxl, outdxs, N, M);
    }
}